// Round 3
// baseline (2102.616 us; speedup 1.0000x reference)
//
#include <hip/hip_runtime.h>
#include <hip/hip_fp16.h>

#define T_TOK 8192
#define H_DIM 1024
#define E_NUM 8
#define I_DIM 1408
#define NSLOT (2 * T_TOK)

typedef __attribute__((ext_vector_type(8))) _Float16 half8;
typedef __attribute__((ext_vector_type(4))) _Float16 half4v;
typedef __attribute__((ext_vector_type(4))) float f32x4;

// ---- static device buffers: fully rewritten every call (graph-safe) ----
__device__ _Float16 g_x16[(size_t)T_TOK * H_DIM];              // x fp16 [T][H]
__device__ _Float16 g_w1t[E_NUM][2][(size_t)I_DIM * H_DIM];    // [e][g/u][n=i][k=h]
__device__ _Float16 g_sw1t[2][(size_t)I_DIM * H_DIM];          // shared g/u [i][h]
__device__ _Float16 g_w2t[E_NUM][(size_t)H_DIM * I_DIM];       // [e][n=h][k=i]
__device__ _Float16 g_sw2t[(size_t)H_DIM * I_DIM];             // shared down [h][i]
__device__ _Float16 g_hbuf[(size_t)(3 * T_TOK + 128) * I_DIM]; // SwiGLU activations
__device__ _Float16 g_dbuf[(size_t)NSLOT * H_DIM];             // routed down-proj

// ---------------- convert x: fp32 -> fp16 ----------------
__global__ __launch_bounds__(256) void convert_x_kernel(const float* __restrict__ x)
{
    int i = (blockIdx.x * 256 + threadIdx.x) * 8;
    float4 v0 = *(const float4*)(x + i);
    float4 v1 = *(const float4*)(x + i + 4);
    half8 h = {(_Float16)v0.x, (_Float16)v0.y, (_Float16)v0.z, (_Float16)v0.w,
               (_Float16)v1.x, (_Float16)v1.y, (_Float16)v1.z, (_Float16)v1.w};
    *(half8*)&g_x16[i] = h;
}

// ---------------- transpose + convert: fp32 [R][C] -> fp16 [C][R] ----------------
__device__ __forceinline__ _Float16* dst_sel(int which, int z) {
    switch (which) {
        case 0: return g_w1t[z][0];
        case 1: return g_w1t[z][1];
        case 2: return g_w2t[z];
        case 3: return g_sw1t[0];
        case 4: return g_sw1t[1];
        default: return g_sw2t;
    }
}

__global__ __launch_bounds__(256) void transconv_kernel(
    const float* __restrict__ src, int which, int R, int C, size_t sstride)
{
    const float* s = src + (size_t)blockIdx.z * sstride;
    _Float16* d = dst_sel(which, blockIdx.z);
    int r0 = blockIdx.y * 64, c0 = blockIdx.x * 64;
    __shared__ float tile[64][65];
    int tr = threadIdx.x >> 4;
    int tc4 = (threadIdx.x & 15) * 4;
#pragma unroll
    for (int it = 0; it < 4; ++it) {
        int r = it * 16 + tr;
        float4 v = *(const float4*)(s + (size_t)(r0 + r) * C + c0 + tc4);
        tile[r][tc4] = v.x; tile[r][tc4 + 1] = v.y;
        tile[r][tc4 + 2] = v.z; tile[r][tc4 + 3] = v.w;
    }
    __syncthreads();
    int tr2 = threadIdx.x >> 3;        // 0..31
    int tc8 = (threadIdx.x & 7) * 8;   // 0..56
#pragma unroll
    for (int it = 0; it < 2; ++it) {
        int c = it * 32 + tr2;         // output row = original column
        half8 h = {(_Float16)tile[tc8 + 0][c], (_Float16)tile[tc8 + 1][c],
                   (_Float16)tile[tc8 + 2][c], (_Float16)tile[tc8 + 3][c],
                   (_Float16)tile[tc8 + 4][c], (_Float16)tile[tc8 + 5][c],
                   (_Float16)tile[tc8 + 6][c], (_Float16)tile[tc8 + 7][c]};
        *(half8*)&d[(size_t)(c0 + c) * R + r0 + tc8] = h;
    }
}

// ---------------- router ----------------
__global__ __launch_bounds__(64) void router_kernel(
    const float* __restrict__ x, const float* __restrict__ gw,
    int* __restrict__ cnt, int* __restrict__ tk_e, float* __restrict__ tk_w)
{
    const int t = blockIdx.x;
    const int lane = threadIdx.x;
    const float* xr = x + (size_t)t * H_DIM;
    float acc[8];
#pragma unroll
    for (int e = 0; e < 8; ++e) acc[e] = 0.f;
    for (int h4 = lane * 4; h4 < H_DIM; h4 += 256) {
        float4 xv = *(const float4*)(xr + h4);
        float xs[4] = {xv.x, xv.y, xv.z, xv.w};
#pragma unroll
        for (int j = 0; j < 4; ++j) {
            const float4* g4 = (const float4*)(gw + (size_t)(h4 + j) * 8);
            float4 ga = g4[0], gb = g4[1];
            acc[0] += xs[j] * ga.x; acc[1] += xs[j] * ga.y;
            acc[2] += xs[j] * ga.z; acc[3] += xs[j] * ga.w;
            acc[4] += xs[j] * gb.x; acc[5] += xs[j] * gb.y;
            acc[6] += xs[j] * gb.z; acc[7] += xs[j] * gb.w;
        }
    }
#pragma unroll
    for (int e = 0; e < 8; ++e) {
#pragma unroll
        for (int off = 32; off > 0; off >>= 1)
            acc[e] += __shfl_xor(acc[e], off, 64);
    }
    if (lane == 0) {
        float mx = acc[0];
#pragma unroll
        for (int e = 1; e < 8; ++e) mx = fmaxf(mx, acc[e]);
        float p[8], sum = 0.f;
#pragma unroll
        for (int e = 0; e < 8; ++e) { p[e] = __expf(acc[e] - mx); sum += p[e]; }
        float inv = 1.f / sum;
#pragma unroll
        for (int e = 0; e < 8; ++e) p[e] *= inv;
        int e0 = 0;
#pragma unroll
        for (int e = 1; e < 8; ++e) if (p[e] > p[e0]) e0 = e;
        int e1 = (e0 == 0) ? 1 : 0;
#pragma unroll
        for (int e = 0; e < 8; ++e) if (e != e0 && p[e] > p[e1]) e1 = e;
        float w0 = p[e0], w1 = p[e1];
        float invw = 1.f / (w0 + w1 + 1e-6f);
        tk_e[2 * t] = e0;          tk_e[2 * t + 1] = e1;
        tk_w[2 * t] = w0 * invw;   tk_w[2 * t + 1] = w1 * invw;
        atomicAdd(&cnt[e0], 1);
        atomicAdd(&cnt[e1], 1);
    }
}

__global__ void scan_kernel(const int* __restrict__ cnt, int* __restrict__ offs)
{
    if (threadIdx.x == 0) {
        int o = 0;
        for (int e = 0; e < 8; ++e) { offs[e] = o; o += cnt[e]; }
    }
}

__global__ __launch_bounds__(256) void scatter_kernel(
    const int* __restrict__ tk_e, const int* __restrict__ offs,
    int* __restrict__ fill, int* __restrict__ tokens, int* __restrict__ slotmap)
{
    int t = blockIdx.x * 256 + threadIdx.x;
    if (t >= T_TOK) return;
#pragma unroll
    for (int k = 0; k < 2; ++k) {
        int e = tk_e[2 * t + k];
        int s = atomicAdd(&fill[e], 1);
        int idx = offs[e] + s;
        tokens[idx] = t;
        slotmap[2 * t + k] = idx;
    }
}

// ---------------- GEMM1: h = silu(X Wg) * (X Wu) ----------------
// BM=128, BN=64 (gate+up), BK=64; register-prefetch pipeline; XOR-swizzled LDS.
__global__ __launch_bounds__(256) void gemm1_kernel(
    const int* __restrict__ cnt, const int* __restrict__ offs,
    const int* __restrict__ tokens)
{
    const int p = blockIdx.z;
    int count, rowbase;
    const _Float16 *Wg, *Wu;
    const int* tokptr = nullptr;
    if (p == 0) {
        count = T_TOK; rowbase = 0; Wg = g_sw1t[0]; Wu = g_sw1t[1];
    } else {
        int e = p - 1;
        count = cnt[e];
        int ob = offs[e];
        rowbase = T_TOK + ob;
        tokptr = tokens + ob;
        Wg = g_w1t[e][0]; Wu = g_w1t[e][1];
    }
    const int m0 = blockIdx.x * 128;
    if (m0 >= count) return;
    const int n0 = blockIdx.y * 64;
    const int tid = threadIdx.x;

    __shared__ _Float16 Asm[128 * 64];
    __shared__ _Float16 Bgs[64 * 64];
    __shared__ _Float16 Bus[64 * 64];
    __shared__ int toksm[128];

    if (tid < 128) {
        int s = m0 + tid;
        int t;
        if (p == 0) t = (s < count) ? s : 0;
        else        t = (s < count) ? tokptr[s] : tokptr[0];
        toksm[tid] = t;
    }
    __syncthreads();

    // staging descriptors: chunk c -> row r=c>>3, slot (cc+r)&7 (XOR swizzle)
    const _Float16* pa[4]; int aoff[4];
#pragma unroll
    for (int i = 0; i < 4; ++i) {
        int c = i * 256 + tid;
        int r = c >> 3, cc = c & 7;
        pa[i] = g_x16 + (size_t)toksm[r] * H_DIM + cc * 8;
        aoff[i] = r * 64 + ((cc + r) & 7) * 8;
    }
    const _Float16 *pg[2], *pu[2]; int boff[2];
#pragma unroll
    for (int i = 0; i < 2; ++i) {
        int c = i * 256 + tid;
        int n = c >> 3, cc = c & 7;
        pg[i] = Wg + (size_t)(n0 + n) * H_DIM + cc * 8;
        pu[i] = Wu + (size_t)(n0 + n) * H_DIM + cc * 8;
        boff[i] = n * 64 + ((cc + n) & 7) * 8;
    }

    const int wid = tid >> 6, lane = tid & 63;
    const int wm = (wid >> 1) * 64, wn = (wid & 1) * 32;
    const int quad = lane >> 4, l16 = lane & 15;

    f32x4 zero4 = {0.f, 0.f, 0.f, 0.f};
    f32x4 accg[4][2], accu[4][2];
#pragma unroll
    for (int mt = 0; mt < 4; ++mt)
#pragma unroll
        for (int nt = 0; nt < 2; ++nt) { accg[mt][nt] = zero4; accu[mt][nt] = zero4; }

    int4 ra[4], rg[2], ru[2];
#pragma unroll
    for (int i = 0; i < 4; ++i) ra[i] = *(const int4*)pa[i];
#pragma unroll
    for (int i = 0; i < 2; ++i) { rg[i] = *(const int4*)pg[i]; ru[i] = *(const int4*)pu[i]; }

    for (int k0 = 0; k0 < H_DIM; k0 += 64) {
        __syncthreads();
#pragma unroll
        for (int i = 0; i < 4; ++i) *(int4*)&Asm[aoff[i]] = ra[i];
#pragma unroll
        for (int i = 0; i < 2; ++i) { *(int4*)&Bgs[boff[i]] = rg[i]; *(int4*)&Bus[boff[i]] = ru[i]; }
        if (k0 + 64 < H_DIM) {   // prefetch next tile into regs; drains during MFMAs
#pragma unroll
            for (int i = 0; i < 4; ++i) ra[i] = *(const int4*)(pa[i] + k0 + 64);
#pragma unroll
            for (int i = 0; i < 2; ++i) { rg[i] = *(const int4*)(pg[i] + k0 + 64);
                                          ru[i] = *(const int4*)(pu[i] + k0 + 64); }
        }
        __syncthreads();

#pragma unroll
        for (int kk = 0; kk < 2; ++kk) {
            half8 a[4], bg2[2], bu2[2];
#pragma unroll
            for (int mt = 0; mt < 4; ++mt) {
                int row = wm + mt * 16 + l16;
                a[mt] = *(const half8*)&Asm[row * 64 + ((kk * 4 + quad + row) & 7) * 8];
            }
#pragma unroll
            for (int nt = 0; nt < 2; ++nt) {
                int row = wn + nt * 16 + l16;
                bg2[nt] = *(const half8*)&Bgs[row * 64 + ((kk * 4 + quad + row) & 7) * 8];
                bu2[nt] = *(const half8*)&Bus[row * 64 + ((kk * 4 + quad + row) & 7) * 8];
            }
#pragma unroll
            for (int mt = 0; mt < 4; ++mt)
#pragma unroll
                for (int nt = 0; nt < 2; ++nt) {
                    accg[mt][nt] = __builtin_amdgcn_mfma_f32_16x16x32_f16(a[mt], bg2[nt], accg[mt][nt], 0, 0, 0);
                    accu[mt][nt] = __builtin_amdgcn_mfma_f32_16x16x32_f16(a[mt], bu2[nt], accu[mt][nt], 0, 0, 0);
                }
        }
    }

#pragma unroll
    for (int mt = 0; mt < 4; ++mt) {
#pragma unroll
        for (int nt = 0; nt < 2; ++nt) {
            int icol = n0 + wn + nt * 16 + l16;
#pragma unroll
            for (int rg2 = 0; rg2 < 4; ++rg2) {
                int s = m0 + wm + mt * 16 + quad * 4 + rg2;
                if (s < count) {
                    float g = accg[mt][nt][rg2];
                    float u = accu[mt][nt][rg2];
                    float hval = (g / (1.f + __expf(-g))) * u;
                    g_hbuf[(size_t)(rowbase + s) * I_DIM + icol] = (_Float16)hval;
                }
            }
        }
    }
}

// ---------------- GEMM2: shared -> out; routed -> dbuf ----------------
// BM=128, BN=128, BK=64; same pipeline structure.
__global__ __launch_bounds__(256) void gemm2_kernel(
    const int* __restrict__ cnt, const int* __restrict__ offs, float* __restrict__ out)
{
    const int p = blockIdx.z;
    int count, hrow, drow = 0;
    const _Float16* W;
    if (p == 0) { count = T_TOK; hrow = 0; W = g_sw2t; }
    else {
        int e = p - 1;
        count = cnt[e];
        int ob = offs[e];
        hrow = T_TOK + ob; drow = ob;
        W = g_w2t[e];
    }
    const int m0 = blockIdx.x * 128;
    if (m0 >= count) return;
    const int n0 = blockIdx.y * 128;
    const int tid = threadIdx.x;

    __shared__ _Float16 Asm[128 * 64];
    __shared__ _Float16 Bsm[128 * 64];

    const _Float16* pa[4]; int aoff[4];
    const _Float16* pb[4]; int boff[4];
#pragma unroll
    for (int i = 0; i < 4; ++i) {
        int c = i * 256 + tid;
        int r = c >> 3, cc = c & 7;
        pa[i] = g_hbuf + (size_t)(hrow + m0 + r) * I_DIM + cc * 8;
        aoff[i] = r * 64 + ((cc + r) & 7) * 8;
        pb[i] = W + (size_t)(n0 + r) * I_DIM + cc * 8;
        boff[i] = aoff[i];
    }

    const int wid = tid >> 6, lane = tid & 63;
    const int wm = (wid >> 1) * 64, wn = (wid & 1) * 64;
    const int quad = lane >> 4, l16 = lane & 15;

    f32x4 zero4 = {0.f, 0.f, 0.f, 0.f};
    f32x4 acc[4][4];
#pragma unroll
    for (int mt = 0; mt < 4; ++mt)
#pragma unroll
        for (int nt = 0; nt < 4; ++nt) acc[mt][nt] = zero4;

    int4 ra[4], rb[4];
#pragma unroll
    for (int i = 0; i < 4; ++i) { ra[i] = *(const int4*)pa[i]; rb[i] = *(const int4*)pb[i]; }

    for (int k0 = 0; k0 < I_DIM; k0 += 64) {
        __syncthreads();
#pragma unroll
        for (int i = 0; i < 4; ++i) { *(int4*)&Asm[aoff[i]] = ra[i]; *(int4*)&Bsm[boff[i]] = rb[i]; }
        if (k0 + 64 < I_DIM) {
#pragma unroll
            for (int i = 0; i < 4; ++i) { ra[i] = *(const int4*)(pa[i] + k0 + 64);
                                          rb[i] = *(const int4*)(pb[i] + k0 + 64); }
        }
        __syncthreads();

#pragma unroll
        for (int kk = 0; kk < 2; ++kk) {
            half8 a[4], b[4];
#pragma unroll
            for (int mt = 0; mt < 4; ++mt) {
                int row = wm + mt * 16 + l16;
                a[mt] = *(const half8*)&Asm[row * 64 + ((kk * 4 + quad + row) & 7) * 8];
            }
#pragma unroll
            for (int nt = 0; nt < 4; ++nt) {
                int row = wn + nt * 16 + l16;
                b[nt] = *(const half8*)&Bsm[row * 64 + ((kk * 4 + quad + row) & 7) * 8];
            }
#pragma unroll
            for (int mt = 0; mt < 4; ++mt)
#pragma unroll
                for (int nt = 0; nt < 4; ++nt)
                    acc[mt][nt] = __builtin_amdgcn_mfma_f32_16x16x32_f16(a[mt], b[nt], acc[mt][nt], 0, 0, 0);
        }
    }

#pragma unroll
    for (int mt = 0; mt < 4; ++mt) {
#pragma unroll
        for (int nt = 0; nt < 4; ++nt) {
            int col = n0 + wn + nt * 16 + l16;
#pragma unroll
            for (int rg = 0; rg < 4; ++rg) {
                int s = m0 + wm + mt * 16 + quad * 4 + rg;
                if (s < count) {
                    float v = acc[mt][nt][rg];
                    if (p == 0) out[(size_t)s * H_DIM + col] = v;
                    else        g_dbuf[(size_t)(drow + s) * H_DIM + col] = (_Float16)v;
                }
            }
        }
    }
}

// ---------------- combine: out[t] += w0*dbuf[s0] + w1*dbuf[s1] ----------------
__global__ __launch_bounds__(256) void combine_kernel(
    const int* __restrict__ slotmap, const float* __restrict__ tk_w,
    float* __restrict__ out)
{
    int t = blockIdx.x;
    int c = threadIdx.x * 4;
    int s0 = slotmap[2 * t], s1 = slotmap[2 * t + 1];
    float w0 = tk_w[2 * t], w1 = tk_w[2 * t + 1];
    float4 o = *(float4*)(out + (size_t)t * H_DIM + c);
    half4v d0 = *(const half4v*)&g_dbuf[(size_t)s0 * H_DIM + c];
    half4v d1 = *(const half4v*)&g_dbuf[(size_t)s1 * H_DIM + c];
    o.x += w0 * (float)d0[0] + w1 * (float)d1[0];
    o.y += w0 * (float)d0[1] + w1 * (float)d1[1];
    o.z += w0 * (float)d0[2] + w1 * (float)d1[2];
    o.w += w0 * (float)d0[3] + w1 * (float)d1[3];
    *(float4*)(out + (size_t)t * H_DIM + c) = o;
}

// ---------------- launch ----------------
extern "C" void kernel_launch(void* const* d_in, const int* in_sizes, int n_in,
                              void* d_out, int out_size, void* d_ws, size_t ws_size,
                              hipStream_t stream)
{
    const float* x  = (const float*)d_in[0];
    const float* gw = (const float*)d_in[1];
    const float* eg = (const float*)d_in[2];
    const float* eu = (const float*)d_in[3];
    const float* ed = (const float*)d_in[4];
    const float* sg = (const float*)d_in[5];
    const float* su = (const float*)d_in[6];
    const float* sd = (const float*)d_in[7];
    float* out = (float*)d_out;

    char* ws = (char*)d_ws;
    int* cnt     = (int*)(ws + 0);
    int* fill    = (int*)(ws + 32);
    int* offs    = (int*)(ws + 64);
    int* tk_e    = (int*)(ws + 128);
    float* tk_w  = (float*)(ws + 128 + 1 * 65536);
    int* tokens  = (int*)(ws + 128 + 2 * 65536);
    int* slotmap = (int*)(ws + 128 + 3 * 65536);

    hipMemsetAsync(ws, 0, 96, stream);

    router_kernel<<<T_TOK, 64, 0, stream>>>(x, gw, cnt, tk_e, tk_w);
    scan_kernel<<<1, 64, 0, stream>>>(cnt, offs);
    scatter_kernel<<<T_TOK / 256, 256, 0, stream>>>(tk_e, offs, fill, tokens, slotmap);

    convert_x_kernel<<<T_TOK * H_DIM / (256 * 8), 256, 0, stream>>>(x);
    transconv_kernel<<<dim3(I_DIM / 64, H_DIM / 64, E_NUM), 256, 0, stream>>>(
        eg, 0, H_DIM, I_DIM, (size_t)H_DIM * I_DIM);
    transconv_kernel<<<dim3(I_DIM / 64, H_DIM / 64, E_NUM), 256, 0, stream>>>(
        eu, 1, H_DIM, I_DIM, (size_t)H_DIM * I_DIM);
    transconv_kernel<<<dim3(H_DIM / 64, I_DIM / 64, E_NUM), 256, 0, stream>>>(
        ed, 2, I_DIM, H_DIM, (size_t)I_DIM * H_DIM);
    transconv_kernel<<<dim3(I_DIM / 64, H_DIM / 64, 1), 256, 0, stream>>>(
        sg, 3, H_DIM, I_DIM, 0);
    transconv_kernel<<<dim3(I_DIM / 64, H_DIM / 64, 1), 256, 0, stream>>>(
        su, 4, H_DIM, I_DIM, 0);
    transconv_kernel<<<dim3(H_DIM / 64, I_DIM / 64, 1), 256, 0, stream>>>(
        sd, 5, I_DIM, H_DIM, 0);

    gemm1_kernel<<<dim3(T_TOK / 128, I_DIM / 64, 9), 256, 0, stream>>>(cnt, offs, tokens);
    gemm2_kernel<<<dim3(T_TOK / 128, H_DIM / 128, 9), 256, 0, stream>>>(cnt, offs, out);
    combine_kernel<<<T_TOK, 256, 0, stream>>>(slotmap, tk_w, out);
}

// Round 4
// 1753.080 us; speedup vs baseline: 1.1994x; 1.1994x over previous
//
#include <hip/hip_runtime.h>
#include <hip/hip_fp16.h>

#define T_TOK 8192
#define H_DIM 1024
#define E_NUM 8
#define I_DIM 1408
#define NSLOT (2 * T_TOK)

typedef __attribute__((ext_vector_type(8))) _Float16 half8;
typedef __attribute__((ext_vector_type(4))) _Float16 half4v;
typedef __attribute__((ext_vector_type(4))) float f32x4;

// ---- static device buffers: fully rewritten every call (graph-safe) ----
__device__ _Float16 g_x16[(size_t)T_TOK * H_DIM];              // x fp16 [T][H]
__device__ _Float16 g_w1t[E_NUM][2][(size_t)I_DIM * H_DIM];    // [e][g/u][n=i][k=h]
__device__ _Float16 g_sw1t[2][(size_t)I_DIM * H_DIM];          // shared g/u [i][h]
__device__ _Float16 g_w2t[E_NUM][(size_t)H_DIM * I_DIM];       // [e][n=h][k=i]
__device__ _Float16 g_sw2t[(size_t)H_DIM * I_DIM];             // shared down [h][i]
__device__ _Float16 g_hbuf[(size_t)(3 * T_TOK + 128) * I_DIM]; // SwiGLU activations
__device__ _Float16 g_dbuf[(size_t)NSLOT * H_DIM];             // routed down-proj

// ---------------- convert x: fp32 -> fp16 ----------------
__global__ __launch_bounds__(256) void convert_x_kernel(const float* __restrict__ x)
{
    int i = (blockIdx.x * 256 + threadIdx.x) * 8;
    float4 v0 = *(const float4*)(x + i);
    float4 v1 = *(const float4*)(x + i + 4);
    half8 h = {(_Float16)v0.x, (_Float16)v0.y, (_Float16)v0.z, (_Float16)v0.w,
               (_Float16)v1.x, (_Float16)v1.y, (_Float16)v1.z, (_Float16)v1.w};
    *(half8*)&g_x16[i] = h;
}

// ---------------- transpose + convert: fp32 [R][C] -> fp16 [C][R] ----------------
__device__ __forceinline__ _Float16* dst_sel(int which, int z) {
    switch (which) {
        case 0: return g_w1t[z][0];
        case 1: return g_w1t[z][1];
        case 2: return g_w2t[z];
        case 3: return g_sw1t[0];
        case 4: return g_sw1t[1];
        default: return g_sw2t;
    }
}

__global__ __launch_bounds__(256) void transconv_kernel(
    const float* __restrict__ src, int which, int R, int C, size_t sstride)
{
    const float* s = src + (size_t)blockIdx.z * sstride;
    _Float16* d = dst_sel(which, blockIdx.z);
    int r0 = blockIdx.y * 64, c0 = blockIdx.x * 64;
    __shared__ float tile[64][65];
    int tr = threadIdx.x >> 4;
    int tc4 = (threadIdx.x & 15) * 4;
#pragma unroll
    for (int it = 0; it < 4; ++it) {
        int r = it * 16 + tr;
        float4 v = *(const float4*)(s + (size_t)(r0 + r) * C + c0 + tc4);
        tile[r][tc4] = v.x; tile[r][tc4 + 1] = v.y;
        tile[r][tc4 + 2] = v.z; tile[r][tc4 + 3] = v.w;
    }
    __syncthreads();
    int tr2 = threadIdx.x >> 3;        // 0..31
    int tc8 = (threadIdx.x & 7) * 8;   // 0..56
#pragma unroll
    for (int it = 0; it < 2; ++it) {
        int c = it * 32 + tr2;         // output row = original column
        half8 h = {(_Float16)tile[tc8 + 0][c], (_Float16)tile[tc8 + 1][c],
                   (_Float16)tile[tc8 + 2][c], (_Float16)tile[tc8 + 3][c],
                   (_Float16)tile[tc8 + 4][c], (_Float16)tile[tc8 + 5][c],
                   (_Float16)tile[tc8 + 6][c], (_Float16)tile[tc8 + 7][c]};
        *(half8*)&d[(size_t)(c0 + c) * R + r0 + tc8] = h;
    }
}

// ---------------- router ----------------
__global__ __launch_bounds__(64) void router_kernel(
    const float* __restrict__ x, const float* __restrict__ gw,
    int* __restrict__ cnt, int* __restrict__ tk_e, float* __restrict__ tk_w)
{
    const int t = blockIdx.x;
    const int lane = threadIdx.x;
    const float* xr = x + (size_t)t * H_DIM;
    float acc[8];
#pragma unroll
    for (int e = 0; e < 8; ++e) acc[e] = 0.f;
    for (int h4 = lane * 4; h4 < H_DIM; h4 += 256) {
        float4 xv = *(const float4*)(xr + h4);
        float xs[4] = {xv.x, xv.y, xv.z, xv.w};
#pragma unroll
        for (int j = 0; j < 4; ++j) {
            const float4* g4 = (const float4*)(gw + (size_t)(h4 + j) * 8);
            float4 ga = g4[0], gb = g4[1];
            acc[0] += xs[j] * ga.x; acc[1] += xs[j] * ga.y;
            acc[2] += xs[j] * ga.z; acc[3] += xs[j] * ga.w;
            acc[4] += xs[j] * gb.x; acc[5] += xs[j] * gb.y;
            acc[6] += xs[j] * gb.z; acc[7] += xs[j] * gb.w;
        }
    }
#pragma unroll
    for (int e = 0; e < 8; ++e) {
#pragma unroll
        for (int off = 32; off > 0; off >>= 1)
            acc[e] += __shfl_xor(acc[e], off, 64);
    }
    if (lane == 0) {
        float mx = acc[0];
#pragma unroll
        for (int e = 1; e < 8; ++e) mx = fmaxf(mx, acc[e]);
        float p[8], sum = 0.f;
#pragma unroll
        for (int e = 0; e < 8; ++e) { p[e] = __expf(acc[e] - mx); sum += p[e]; }
        float inv = 1.f / sum;
#pragma unroll
        for (int e = 0; e < 8; ++e) p[e] *= inv;
        int e0 = 0;
#pragma unroll
        for (int e = 1; e < 8; ++e) if (p[e] > p[e0]) e0 = e;
        int e1 = (e0 == 0) ? 1 : 0;
#pragma unroll
        for (int e = 0; e < 8; ++e) if (e != e0 && p[e] > p[e1]) e1 = e;
        float w0 = p[e0], w1 = p[e1];
        float invw = 1.f / (w0 + w1 + 1e-6f);
        tk_e[2 * t] = e0;          tk_e[2 * t + 1] = e1;
        tk_w[2 * t] = w0 * invw;   tk_w[2 * t + 1] = w1 * invw;
        atomicAdd(&cnt[e0], 1);
        atomicAdd(&cnt[e1], 1);
    }
}

__global__ void scan_kernel(const int* __restrict__ cnt, int* __restrict__ offs)
{
    if (threadIdx.x == 0) {
        int o = 0;
        for (int e = 0; e < 8; ++e) { offs[e] = o; o += cnt[e]; }
    }
}

__global__ __launch_bounds__(256) void scatter_kernel(
    const int* __restrict__ tk_e, const int* __restrict__ offs,
    int* __restrict__ fill, int* __restrict__ tokens, int* __restrict__ slotmap)
{
    int t = blockIdx.x * 256 + threadIdx.x;
    if (t >= T_TOK) return;
#pragma unroll
    for (int k = 0; k < 2; ++k) {
        int e = tk_e[2 * t + k];
        int s = atomicAdd(&fill[e], 1);
        int idx = offs[e] + s;
        tokens[idx] = t;
        slotmap[2 * t + k] = idx;
    }
}

// ================= GEMM1: h = silu(X Wg) * (X Wu) =================
// No LDS tiles, no inner barriers: each lane b128-loads its MFMA fragments
// directly from global (L1/L2/L3-fed). Block 128m x 64n; wave = 64m x 32n.
#define G1_LOAD(A, BG, BU, KOFF)                                        \
    do {                                                                \
        _Pragma("unroll")                                               \
        for (int mt = 0; mt < 4; ++mt) A[mt] = *(const half8*)(pA[mt] + (KOFF)); \
        _Pragma("unroll")                                               \
        for (int nt = 0; nt < 2; ++nt) {                                \
            BG[nt] = *(const half8*)(pBg[nt] + (KOFF));                 \
            BU[nt] = *(const half8*)(pBu[nt] + (KOFF));                 \
        }                                                               \
    } while (0)

#define G1_MFMA(A, BG, BU)                                              \
    do {                                                                \
        _Pragma("unroll")                                               \
        for (int mt = 0; mt < 4; ++mt)                                  \
            _Pragma("unroll")                                           \
            for (int nt = 0; nt < 2; ++nt) {                            \
                accg[mt][nt] = __builtin_amdgcn_mfma_f32_16x16x32_f16(A[mt], BG[nt], accg[mt][nt], 0, 0, 0); \
                accu[mt][nt] = __builtin_amdgcn_mfma_f32_16x16x32_f16(A[mt], BU[nt], accu[mt][nt], 0, 0, 0); \
            }                                                           \
    } while (0)

__global__ __launch_bounds__(256) void gemm1_kernel(
    const int* __restrict__ cnt, const int* __restrict__ offs,
    const int* __restrict__ tokens)
{
    const int p = blockIdx.z;
    int count, rowbase;
    const _Float16 *Wg, *Wu;
    const int* tokptr = nullptr;
    if (p == 0) {
        count = T_TOK; rowbase = 0; Wg = g_sw1t[0]; Wu = g_sw1t[1];
    } else {
        int e = p - 1;
        count = cnt[e];
        int ob = offs[e];
        rowbase = T_TOK + ob;
        tokptr = tokens + ob;
        Wg = g_w1t[e][0]; Wu = g_w1t[e][1];
    }
    const int m0 = blockIdx.x * 128;
    if (m0 >= count) return;
    const int n0 = blockIdx.y * 64;
    const int tid = threadIdx.x;

    __shared__ int toksm[128];
    if (tid < 128) {
        int s = m0 + tid;
        int t;
        if (p == 0) t = (s < count) ? s : 0;
        else        t = (s < count) ? tokptr[s] : tokptr[0];
        toksm[tid] = t;
    }
    __syncthreads();

    const int wid = tid >> 6, lane = tid & 63;
    const int wm = (wid >> 1) * 64, wn = (wid & 1) * 32;
    const int quad = lane >> 4, l16 = lane & 15;

    // per-lane fragment base pointers (+k0 elements walks K)
    const _Float16* pA[4];
#pragma unroll
    for (int mt = 0; mt < 4; ++mt)
        pA[mt] = g_x16 + (size_t)toksm[wm + mt * 16 + l16] * H_DIM + quad * 8;
    const _Float16 *pBg[2], *pBu[2];
#pragma unroll
    for (int nt = 0; nt < 2; ++nt) {
        int n = n0 + wn + nt * 16 + l16;
        pBg[nt] = Wg + (size_t)n * H_DIM + quad * 8;
        pBu[nt] = Wu + (size_t)n * H_DIM + quad * 8;
    }

    f32x4 zero4 = {0.f, 0.f, 0.f, 0.f};
    f32x4 accg[4][2], accu[4][2];
#pragma unroll
    for (int mt = 0; mt < 4; ++mt)
#pragma unroll
        for (int nt = 0; nt < 2; ++nt) { accg[mt][nt] = zero4; accu[mt][nt] = zero4; }

    half8 a0[4], bg0[2], bu0[2], a1[4], bg1[2], bu1[2];
    G1_LOAD(a0, bg0, bu0, 0);
    for (int k0 = 0; k0 < H_DIM - 64; k0 += 64) {
        G1_LOAD(a1, bg1, bu1, k0 + 32);
        G1_MFMA(a0, bg0, bu0);
        G1_LOAD(a0, bg0, bu0, k0 + 64);
        G1_MFMA(a1, bg1, bu1);
    }
    G1_LOAD(a1, bg1, bu1, H_DIM - 32);
    G1_MFMA(a0, bg0, bu0);
    G1_MFMA(a1, bg1, bu1);

#pragma unroll
    for (int mt = 0; mt < 4; ++mt) {
#pragma unroll
        for (int nt = 0; nt < 2; ++nt) {
            int icol = n0 + wn + nt * 16 + l16;
#pragma unroll
            for (int rg = 0; rg < 4; ++rg) {
                int s = m0 + wm + mt * 16 + quad * 4 + rg;
                if (s < count) {
                    float g = accg[mt][nt][rg];
                    float u = accu[mt][nt][rg];
                    float hval = (g / (1.f + __expf(-g))) * u;
                    g_hbuf[(size_t)(rowbase + s) * I_DIM + icol] = (_Float16)hval;
                }
            }
        }
    }
}

// ================= GEMM2: shared -> out; routed -> dbuf =================
// Block 128m x 128n; wave = 64m x 64n; same no-LDS register-fragment flow.
#define G2_LOAD(A, B, KOFF)                                             \
    do {                                                                \
        _Pragma("unroll")                                               \
        for (int mt = 0; mt < 4; ++mt) A[mt] = *(const half8*)(pA[mt] + (KOFF)); \
        _Pragma("unroll")                                               \
        for (int nt = 0; nt < 4; ++nt) B[nt] = *(const half8*)(pB[nt] + (KOFF)); \
    } while (0)

#define G2_MFMA(A, B)                                                   \
    do {                                                                \
        _Pragma("unroll")                                               \
        for (int mt = 0; mt < 4; ++mt)                                  \
            _Pragma("unroll")                                           \
            for (int nt = 0; nt < 4; ++nt)                              \
                acc[mt][nt] = __builtin_amdgcn_mfma_f32_16x16x32_f16(A[mt], B[nt], acc[mt][nt], 0, 0, 0); \
    } while (0)

__global__ __launch_bounds__(256) void gemm2_kernel(
    const int* __restrict__ cnt, const int* __restrict__ offs, float* __restrict__ out)
{
    const int p = blockIdx.z;
    int count, hrow, drow = 0;
    const _Float16* W;
    if (p == 0) { count = T_TOK; hrow = 0; W = g_sw2t; }
    else {
        int e = p - 1;
        count = cnt[e];
        int ob = offs[e];
        hrow = T_TOK + ob; drow = ob;
        W = g_w2t[e];
    }
    const int m0 = blockIdx.x * 128;
    if (m0 >= count) return;
    const int n0 = blockIdx.y * 128;
    const int tid = threadIdx.x;

    const int wid = tid >> 6, lane = tid & 63;
    const int wm = (wid >> 1) * 64, wn = (wid & 1) * 64;
    const int quad = lane >> 4, l16 = lane & 15;

    const _Float16* pA[4];
#pragma unroll
    for (int mt = 0; mt < 4; ++mt)
        pA[mt] = g_hbuf + (size_t)(hrow + m0 + wm + mt * 16 + l16) * I_DIM + quad * 8;
    const _Float16* pB[4];
#pragma unroll
    for (int nt = 0; nt < 4; ++nt)
        pB[nt] = W + (size_t)(n0 + wn + nt * 16 + l16) * I_DIM + quad * 8;

    f32x4 zero4 = {0.f, 0.f, 0.f, 0.f};
    f32x4 acc[4][4];
#pragma unroll
    for (int mt = 0; mt < 4; ++mt)
#pragma unroll
        for (int nt = 0; nt < 4; ++nt) acc[mt][nt] = zero4;

    half8 a0[4], b0[4], a1[4], b1[4];
    G2_LOAD(a0, b0, 0);
    for (int k0 = 0; k0 < I_DIM - 64; k0 += 64) {
        G2_LOAD(a1, b1, k0 + 32);
        G2_MFMA(a0, b0);
        G2_LOAD(a0, b0, k0 + 64);
        G2_MFMA(a1, b1);
    }
    G2_LOAD(a1, b1, I_DIM - 32);
    G2_MFMA(a0, b0);
    G2_MFMA(a1, b1);

#pragma unroll
    for (int mt = 0; mt < 4; ++mt) {
#pragma unroll
        for (int nt = 0; nt < 4; ++nt) {
            int col = n0 + wn + nt * 16 + l16;
#pragma unroll
            for (int rg = 0; rg < 4; ++rg) {
                int s = m0 + wm + mt * 16 + quad * 4 + rg;
                if (s < count) {
                    float v = acc[mt][nt][rg];
                    if (p == 0) out[(size_t)s * H_DIM + col] = v;
                    else        g_dbuf[(size_t)(drow + s) * H_DIM + col] = (_Float16)v;
                }
            }
        }
    }
}

// ---------------- combine: out[t] += w0*dbuf[s0] + w1*dbuf[s1] ----------------
__global__ __launch_bounds__(256) void combine_kernel(
    const int* __restrict__ slotmap, const float* __restrict__ tk_w,
    float* __restrict__ out)
{
    int t = blockIdx.x;
    int c = threadIdx.x * 4;
    int s0 = slotmap[2 * t], s1 = slotmap[2 * t + 1];
    float w0 = tk_w[2 * t], w1 = tk_w[2 * t + 1];
    float4 o = *(float4*)(out + (size_t)t * H_DIM + c);
    half4v d0 = *(const half4v*)&g_dbuf[(size_t)s0 * H_DIM + c];
    half4v d1 = *(const half4v*)&g_dbuf[(size_t)s1 * H_DIM + c];
    o.x += w0 * (float)d0[0] + w1 * (float)d1[0];
    o.y += w0 * (float)d0[1] + w1 * (float)d1[1];
    o.z += w0 * (float)d0[2] + w1 * (float)d1[2];
    o.w += w0 * (float)d0[3] + w1 * (float)d1[3];
    *(float4*)(out + (size_t)t * H_DIM + c) = o;
}

// ---------------- launch ----------------
extern "C" void kernel_launch(void* const* d_in, const int* in_sizes, int n_in,
                              void* d_out, int out_size, void* d_ws, size_t ws_size,
                              hipStream_t stream)
{
    const float* x  = (const float*)d_in[0];
    const float* gw = (const float*)d_in[1];
    const float* eg = (const float*)d_in[2];
    const float* eu = (const float*)d_in[3];
    const float* ed = (const float*)d_in[4];
    const float* sg = (const float*)d_in[5];
    const float* su = (const float*)d_in[6];
    const float* sd = (const float*)d_in[7];
    float* out = (float*)d_out;

    char* ws = (char*)d_ws;
    int* cnt     = (int*)(ws + 0);
    int* fill    = (int*)(ws + 32);
    int* offs    = (int*)(ws + 64);
    int* tk_e    = (int*)(ws + 128);
    float* tk_w  = (float*)(ws + 128 + 1 * 65536);
    int* tokens  = (int*)(ws + 128 + 2 * 65536);
    int* slotmap = (int*)(ws + 128 + 3 * 65536);

    hipMemsetAsync(ws, 0, 96, stream);

    router_kernel<<<T_TOK, 64, 0, stream>>>(x, gw, cnt, tk_e, tk_w);
    scan_kernel<<<1, 64, 0, stream>>>(cnt, offs);
    scatter_kernel<<<T_TOK / 256, 256, 0, stream>>>(tk_e, offs, fill, tokens, slotmap);

    convert_x_kernel<<<T_TOK * H_DIM / (256 * 8), 256, 0, stream>>>(x);
    transconv_kernel<<<dim3(I_DIM / 64, H_DIM / 64, E_NUM), 256, 0, stream>>>(
        eg, 0, H_DIM, I_DIM, (size_t)H_DIM * I_DIM);
    transconv_kernel<<<dim3(I_DIM / 64, H_DIM / 64, E_NUM), 256, 0, stream>>>(
        eu, 1, H_DIM, I_DIM, (size_t)H_DIM * I_DIM);
    transconv_kernel<<<dim3(H_DIM / 64, I_DIM / 64, E_NUM), 256, 0, stream>>>(
        ed, 2, I_DIM, H_DIM, (size_t)I_DIM * H_DIM);
    transconv_kernel<<<dim3(I_DIM / 64, H_DIM / 64, 1), 256, 0, stream>>>(
        sg, 3, H_DIM, I_DIM, 0);
    transconv_kernel<<<dim3(I_DIM / 64, H_DIM / 64, 1), 256, 0, stream>>>(
        su, 4, H_DIM, I_DIM, 0);
    transconv_kernel<<<dim3(H_DIM / 64, I_DIM / 64, 1), 256, 0, stream>>>(
        sd, 5, I_DIM, H_DIM, 0);

    gemm1_kernel<<<dim3(T_TOK / 128, I_DIM / 64, 9), 256, 0, stream>>>(cnt, offs, tokens);
    gemm2_kernel<<<dim3(T_TOK / 128, H_DIM / 128, 9), 256, 0, stream>>>(cnt, offs, out);
    combine_kernel<<<T_TOK, 256, 0, stream>>>(slotmap, tk_w, out);
}

// Round 5
// 1139.117 us; speedup vs baseline: 1.8458x; 1.5390x over previous
//
#include <hip/hip_runtime.h>
#include <hip/hip_fp16.h>

#define T_TOK 8192
#define H_DIM 1024
#define E_NUM 8
#define I_DIM 1408
#define NSLOT (2 * T_TOK)

typedef __attribute__((ext_vector_type(8))) _Float16 half8;
typedef __attribute__((ext_vector_type(4))) _Float16 half4v;
typedef __attribute__((ext_vector_type(4))) float f32x4;

// ---- static device buffers: fully rewritten every call (graph-safe) ----
__device__ _Float16 g_x16[(size_t)T_TOK * H_DIM];              // x fp16 [T][H]
__device__ _Float16 g_w1t[E_NUM][2][(size_t)I_DIM * H_DIM];    // [e][g/u][n=i][k=h]
__device__ _Float16 g_sw1t[2][(size_t)I_DIM * H_DIM];          // shared g/u [i][h]
__device__ _Float16 g_w2t[E_NUM][(size_t)H_DIM * I_DIM];       // [e][n=h][k=i]
__device__ _Float16 g_sw2t[(size_t)H_DIM * I_DIM];             // shared down [h][i]
__device__ _Float16 g_hbuf[(size_t)(3 * T_TOK + 128) * I_DIM]; // SwiGLU activations
__device__ _Float16 g_dbuf[(size_t)NSLOT * H_DIM];             // routed down-proj

// ---------------- convert x: fp32 -> fp16 ----------------
__global__ __launch_bounds__(256) void convert_x_kernel(const float* __restrict__ x)
{
    int i = (blockIdx.x * 256 + threadIdx.x) * 8;
    float4 v0 = *(const float4*)(x + i);
    float4 v1 = *(const float4*)(x + i + 4);
    half8 h = {(_Float16)v0.x, (_Float16)v0.y, (_Float16)v0.z, (_Float16)v0.w,
               (_Float16)v1.x, (_Float16)v1.y, (_Float16)v1.z, (_Float16)v1.w};
    *(half8*)&g_x16[i] = h;
}

// ---------------- transpose + convert: fp32 [R][C] -> fp16 [C][R] ----------------
__device__ __forceinline__ _Float16* dst_sel(int which, int z) {
    switch (which) {
        case 0: return g_w1t[z][0];
        case 1: return g_w1t[z][1];
        case 2: return g_w2t[z];
        case 3: return g_sw1t[0];
        case 4: return g_sw1t[1];
        default: return g_sw2t;
    }
}

__global__ __launch_bounds__(256) void transconv_kernel(
    const float* __restrict__ src, int which, int R, int C, size_t sstride)
{
    const float* s = src + (size_t)blockIdx.z * sstride;
    _Float16* d = dst_sel(which, blockIdx.z);
    int r0 = blockIdx.y * 64, c0 = blockIdx.x * 64;
    __shared__ float tile[64][65];
    int tr = threadIdx.x >> 4;
    int tc4 = (threadIdx.x & 15) * 4;
#pragma unroll
    for (int it = 0; it < 4; ++it) {
        int r = it * 16 + tr;
        float4 v = *(const float4*)(s + (size_t)(r0 + r) * C + c0 + tc4);
        tile[r][tc4] = v.x; tile[r][tc4 + 1] = v.y;
        tile[r][tc4 + 2] = v.z; tile[r][tc4 + 3] = v.w;
    }
    __syncthreads();
    int tr2 = threadIdx.x >> 3;        // 0..31
    int tc8 = (threadIdx.x & 7) * 8;   // 0..56
#pragma unroll
    for (int it = 0; it < 2; ++it) {
        int c = it * 32 + tr2;         // output row = original column
        half8 h = {(_Float16)tile[tc8 + 0][c], (_Float16)tile[tc8 + 1][c],
                   (_Float16)tile[tc8 + 2][c], (_Float16)tile[tc8 + 3][c],
                   (_Float16)tile[tc8 + 4][c], (_Float16)tile[tc8 + 5][c],
                   (_Float16)tile[tc8 + 6][c], (_Float16)tile[tc8 + 7][c]};
        *(half8*)&d[(size_t)(c0 + c) * R + r0 + tc8] = h;
    }
}

// ---------------- router ----------------
__global__ __launch_bounds__(64) void router_kernel(
    const float* __restrict__ x, const float* __restrict__ gw,
    int* __restrict__ cnt, int* __restrict__ tk_e, float* __restrict__ tk_w)
{
    const int t = blockIdx.x;
    const int lane = threadIdx.x;
    const float* xr = x + (size_t)t * H_DIM;
    float acc[8];
#pragma unroll
    for (int e = 0; e < 8; ++e) acc[e] = 0.f;
    for (int h4 = lane * 4; h4 < H_DIM; h4 += 256) {
        float4 xv = *(const float4*)(xr + h4);
        float xs[4] = {xv.x, xv.y, xv.z, xv.w};
#pragma unroll
        for (int j = 0; j < 4; ++j) {
            const float4* g4 = (const float4*)(gw + (size_t)(h4 + j) * 8);
            float4 ga = g4[0], gb = g4[1];
            acc[0] += xs[j] * ga.x; acc[1] += xs[j] * ga.y;
            acc[2] += xs[j] * ga.z; acc[3] += xs[j] * ga.w;
            acc[4] += xs[j] * gb.x; acc[5] += xs[j] * gb.y;
            acc[6] += xs[j] * gb.z; acc[7] += xs[j] * gb.w;
        }
    }
#pragma unroll
    for (int e = 0; e < 8; ++e) {
#pragma unroll
        for (int off = 32; off > 0; off >>= 1)
            acc[e] += __shfl_xor(acc[e], off, 64);
    }
    if (lane == 0) {
        float mx = acc[0];
#pragma unroll
        for (int e = 1; e < 8; ++e) mx = fmaxf(mx, acc[e]);
        float p[8], sum = 0.f;
#pragma unroll
        for (int e = 0; e < 8; ++e) { p[e] = __expf(acc[e] - mx); sum += p[e]; }
        float inv = 1.f / sum;
#pragma unroll
        for (int e = 0; e < 8; ++e) p[e] *= inv;
        int e0 = 0;
#pragma unroll
        for (int e = 1; e < 8; ++e) if (p[e] > p[e0]) e0 = e;
        int e1 = (e0 == 0) ? 1 : 0;
#pragma unroll
        for (int e = 0; e < 8; ++e) if (e != e0 && p[e] > p[e1]) e1 = e;
        float w0 = p[e0], w1 = p[e1];
        float invw = 1.f / (w0 + w1 + 1e-6f);
        tk_e[2 * t] = e0;          tk_e[2 * t + 1] = e1;
        tk_w[2 * t] = w0 * invw;   tk_w[2 * t + 1] = w1 * invw;
        atomicAdd(&cnt[e0], 1);
        atomicAdd(&cnt[e1], 1);
    }
}

__global__ void scan_kernel(const int* __restrict__ cnt, int* __restrict__ offs)
{
    if (threadIdx.x == 0) {
        int o = 0;
        for (int e = 0; e < 8; ++e) { offs[e] = o; o += cnt[e]; }
    }
}

__global__ __launch_bounds__(256) void scatter_kernel(
    const int* __restrict__ tk_e, const int* __restrict__ offs,
    int* __restrict__ fill, int* __restrict__ tokens, int* __restrict__ slotmap)
{
    int t = blockIdx.x * 256 + threadIdx.x;
    if (t >= T_TOK) return;
#pragma unroll
    for (int k = 0; k < 2; ++k) {
        int e = tk_e[2 * t + k];
        int s = atomicAdd(&fill[e], 1);
        int idx = offs[e] + s;
        tokens[idx] = t;
        slotmap[2 * t + k] = idx;
    }
}

// ================= GEMM1: h = silu(X Wg) * (X Wu) =================
// r1-style pipeline: global->VGPR->ds_write, 2 barriers, BK=32, fp16 operands,
// XOR-swizzled LDS (chunk slot (cc+row)&3), block 128m x 64i (g+u).
__global__ __launch_bounds__(256) void gemm1_kernel(
    const int* __restrict__ cnt, const int* __restrict__ offs,
    const int* __restrict__ tokens)
{
    const int p = blockIdx.z;
    int count, rowbase;
    const _Float16 *Wg, *Wu;
    const int* tokptr = nullptr;
    if (p == 0) {
        count = T_TOK; rowbase = 0; Wg = g_sw1t[0]; Wu = g_sw1t[1];
    } else {
        int e = p - 1;
        count = cnt[e];
        int ob = offs[e];
        rowbase = T_TOK + ob;
        tokptr = tokens + ob;
        Wg = g_w1t[e][0]; Wu = g_w1t[e][1];
    }
    const int m0 = blockIdx.x * 128;
    if (m0 >= count) return;
    const int n0 = blockIdx.y * 64;
    const int tid = threadIdx.x;

    __shared__ _Float16 Asm[128 * 32];
    __shared__ _Float16 Bgs[64 * 32];
    __shared__ _Float16 Bus[64 * 32];
    __shared__ int toksm[128];

    if (tid < 128) {
        int s = m0 + tid;
        int t;
        if (p == 0) t = (s < count) ? s : 0;
        else        t = (s < count) ? tokptr[s] : tokptr[0];
        toksm[tid] = t;
    }
    __syncthreads();

    // A: 128 rows x 4 chunks -> 2 chunks/thread. B: 64 rows x 4 -> 1 chunk each.
    const int rA0 = tid >> 2, rA1 = (256 + tid) >> 2, ccA = tid & 3;
    const _Float16* pa0 = g_x16 + (size_t)toksm[rA0] * H_DIM + ccA * 8;
    const _Float16* pa1 = g_x16 + (size_t)toksm[rA1] * H_DIM + ccA * 8;
    const int aoff0 = rA0 * 32 + ((ccA + rA0) & 3) * 8;
    const int aoff1 = rA1 * 32 + ((ccA + rA1) & 3) * 8;
    const int nB = tid >> 2;
    const _Float16* pbg = Wg + (size_t)(n0 + nB) * H_DIM + ccA * 8;
    const _Float16* pbu = Wu + (size_t)(n0 + nB) * H_DIM + ccA * 8;
    const int boff = nB * 32 + ((ccA + nB) & 3) * 8;

    const int wid = tid >> 6, lane = tid & 63;
    const int wm = (wid >> 1) * 64, wn = (wid & 1) * 32;
    const int quad = lane >> 4, l16 = lane & 15;

    f32x4 zero4 = {0.f, 0.f, 0.f, 0.f};
    f32x4 accg[4][2], accu[4][2];
#pragma unroll
    for (int mt = 0; mt < 4; ++mt)
#pragma unroll
        for (int nt = 0; nt < 2; ++nt) { accg[mt][nt] = zero4; accu[mt][nt] = zero4; }

    for (int k0 = 0; k0 < H_DIM; k0 += 32) {
        int4 va0 = *(const int4*)(pa0 + k0);
        int4 va1 = *(const int4*)(pa1 + k0);
        int4 vbg = *(const int4*)(pbg + k0);
        int4 vbu = *(const int4*)(pbu + k0);
        *(int4*)&Asm[aoff0] = va0;
        *(int4*)&Asm[aoff1] = va1;
        *(int4*)&Bgs[boff]  = vbg;
        *(int4*)&Bus[boff]  = vbu;
        __syncthreads();

        half8 a[4], bg2[2], bu2[2];
#pragma unroll
        for (int mt = 0; mt < 4; ++mt) {
            int row = wm + mt * 16 + l16;
            a[mt] = *(const half8*)&Asm[row * 32 + ((quad + row) & 3) * 8];
        }
#pragma unroll
        for (int nt = 0; nt < 2; ++nt) {
            int row = wn + nt * 16 + l16;
            bg2[nt] = *(const half8*)&Bgs[row * 32 + ((quad + row) & 3) * 8];
            bu2[nt] = *(const half8*)&Bus[row * 32 + ((quad + row) & 3) * 8];
        }
#pragma unroll
        for (int mt = 0; mt < 4; ++mt)
#pragma unroll
            for (int nt = 0; nt < 2; ++nt) {
                accg[mt][nt] = __builtin_amdgcn_mfma_f32_16x16x32_f16(a[mt], bg2[nt], accg[mt][nt], 0, 0, 0);
                accu[mt][nt] = __builtin_amdgcn_mfma_f32_16x16x32_f16(a[mt], bu2[nt], accu[mt][nt], 0, 0, 0);
            }
        __syncthreads();
    }

#pragma unroll
    for (int mt = 0; mt < 4; ++mt) {
#pragma unroll
        for (int nt = 0; nt < 2; ++nt) {
            int icol = n0 + wn + nt * 16 + l16;
#pragma unroll
            for (int rg = 0; rg < 4; ++rg) {
                int s = m0 + wm + mt * 16 + quad * 4 + rg;
                if (s < count) {
                    float g = accg[mt][nt][rg];
                    float u = accu[mt][nt][rg];
                    float hval = (g / (1.f + __expf(-g))) * u;
                    g_hbuf[(size_t)(rowbase + s) * I_DIM + icol] = (_Float16)hval;
                }
            }
        }
    }
}

// ================= GEMM2: shared -> out; routed -> dbuf =================
// Same pipeline; block 128m x 128n, wave 64x64, BK=32.
__global__ __launch_bounds__(256) void gemm2_kernel(
    const int* __restrict__ cnt, const int* __restrict__ offs, float* __restrict__ out)
{
    const int p = blockIdx.z;
    int count, hrow, drow = 0;
    const _Float16* W;
    if (p == 0) { count = T_TOK; hrow = 0; W = g_sw2t; }
    else {
        int e = p - 1;
        count = cnt[e];
        int ob = offs[e];
        hrow = T_TOK + ob; drow = ob;
        W = g_w2t[e];
    }
    const int m0 = blockIdx.x * 128;
    if (m0 >= count) return;
    const int n0 = blockIdx.y * 128;
    const int tid = threadIdx.x;

    __shared__ _Float16 Asm[128 * 32];
    __shared__ _Float16 Bsm[128 * 32];

    const int r0 = tid >> 2, r1 = (256 + tid) >> 2, cc = tid & 3;
    const _Float16* pa0 = g_hbuf + (size_t)(hrow + m0 + r0) * I_DIM + cc * 8;
    const _Float16* pa1 = g_hbuf + (size_t)(hrow + m0 + r1) * I_DIM + cc * 8;
    const _Float16* pb0 = W + (size_t)(n0 + r0) * I_DIM + cc * 8;
    const _Float16* pb1 = W + (size_t)(n0 + r1) * I_DIM + cc * 8;
    const int off0 = r0 * 32 + ((cc + r0) & 3) * 8;
    const int off1 = r1 * 32 + ((cc + r1) & 3) * 8;

    const int wid = tid >> 6, lane = tid & 63;
    const int wm = (wid >> 1) * 64, wn = (wid & 1) * 64;
    const int quad = lane >> 4, l16 = lane & 15;

    f32x4 zero4 = {0.f, 0.f, 0.f, 0.f};
    f32x4 acc[4][4];
#pragma unroll
    for (int mt = 0; mt < 4; ++mt)
#pragma unroll
        for (int nt = 0; nt < 4; ++nt) acc[mt][nt] = zero4;

    for (int k0 = 0; k0 < I_DIM; k0 += 32) {
        int4 va0 = *(const int4*)(pa0 + k0);
        int4 va1 = *(const int4*)(pa1 + k0);
        int4 vb0 = *(const int4*)(pb0 + k0);
        int4 vb1 = *(const int4*)(pb1 + k0);
        *(int4*)&Asm[off0] = va0;
        *(int4*)&Asm[off1] = va1;
        *(int4*)&Bsm[off0] = vb0;
        *(int4*)&Bsm[off1] = vb1;
        __syncthreads();

        half8 a[4], b[4];
#pragma unroll
        for (int mt = 0; mt < 4; ++mt) {
            int row = wm + mt * 16 + l16;
            a[mt] = *(const half8*)&Asm[row * 32 + ((quad + row) & 3) * 8];
        }
#pragma unroll
        for (int nt = 0; nt < 4; ++nt) {
            int row = wn + nt * 16 + l16;
            b[nt] = *(const half8*)&Bsm[row * 32 + ((quad + row) & 3) * 8];
        }
#pragma unroll
        for (int mt = 0; mt < 4; ++mt)
#pragma unroll
            for (int nt = 0; nt < 4; ++nt)
                acc[mt][nt] = __builtin_amdgcn_mfma_f32_16x16x32_f16(a[mt], b[nt], acc[mt][nt], 0, 0, 0);
        __syncthreads();
    }

#pragma unroll
    for (int mt = 0; mt < 4; ++mt) {
#pragma unroll
        for (int nt = 0; nt < 4; ++nt) {
            int col = n0 + wn + nt * 16 + l16;
#pragma unroll
            for (int rg = 0; rg < 4; ++rg) {
                int s = m0 + wm + mt * 16 + quad * 4 + rg;
                if (s < count) {
                    float v = acc[mt][nt][rg];
                    if (p == 0) out[(size_t)s * H_DIM + col] = v;
                    else        g_dbuf[(size_t)(drow + s) * H_DIM + col] = (_Float16)v;
                }
            }
        }
    }
}

// ---------------- combine: out[t] += w0*dbuf[s0] + w1*dbuf[s1] ----------------
__global__ __launch_bounds__(256) void combine_kernel(
    const int* __restrict__ slotmap, const float* __restrict__ tk_w,
    float* __restrict__ out)
{
    int t = blockIdx.x;
    int c = threadIdx.x * 4;
    int s0 = slotmap[2 * t], s1 = slotmap[2 * t + 1];
    float w0 = tk_w[2 * t], w1 = tk_w[2 * t + 1];
    float4 o = *(float4*)(out + (size_t)t * H_DIM + c);
    half4v d0 = *(const half4v*)&g_dbuf[(size_t)s0 * H_DIM + c];
    half4v d1 = *(const half4v*)&g_dbuf[(size_t)s1 * H_DIM + c];
    o.x += w0 * (float)d0[0] + w1 * (float)d1[0];
    o.y += w0 * (float)d0[1] + w1 * (float)d1[1];
    o.z += w0 * (float)d0[2] + w1 * (float)d1[2];
    o.w += w0 * (float)d0[3] + w1 * (float)d1[3];
    *(float4*)(out + (size_t)t * H_DIM + c) = o;
}

// ---------------- launch ----------------
extern "C" void kernel_launch(void* const* d_in, const int* in_sizes, int n_in,
                              void* d_out, int out_size, void* d_ws, size_t ws_size,
                              hipStream_t stream)
{
    const float* x  = (const float*)d_in[0];
    const float* gw = (const float*)d_in[1];
    const float* eg = (const float*)d_in[2];
    const float* eu = (const float*)d_in[3];
    const float* ed = (const float*)d_in[4];
    const float* sg = (const float*)d_in[5];
    const float* su = (const float*)d_in[6];
    const float* sd = (const float*)d_in[7];
    float* out = (float*)d_out;

    char* ws = (char*)d_ws;
    int* cnt     = (int*)(ws + 0);
    int* fill    = (int*)(ws + 32);
    int* offs    = (int*)(ws + 64);
    int* tk_e    = (int*)(ws + 128);
    float* tk_w  = (float*)(ws + 128 + 1 * 65536);
    int* tokens  = (int*)(ws + 128 + 2 * 65536);
    int* slotmap = (int*)(ws + 128 + 3 * 65536);

    hipMemsetAsync(ws, 0, 96, stream);

    router_kernel<<<T_TOK, 64, 0, stream>>>(x, gw, cnt, tk_e, tk_w);
    scan_kernel<<<1, 64, 0, stream>>>(cnt, offs);
    scatter_kernel<<<T_TOK / 256, 256, 0, stream>>>(tk_e, offs, fill, tokens, slotmap);

    convert_x_kernel<<<T_TOK * H_DIM / (256 * 8), 256, 0, stream>>>(x);
    transconv_kernel<<<dim3(I_DIM / 64, H_DIM / 64, E_NUM), 256, 0, stream>>>(
        eg, 0, H_DIM, I_DIM, (size_t)H_DIM * I_DIM);
    transconv_kernel<<<dim3(I_DIM / 64, H_DIM / 64, E_NUM), 256, 0, stream>>>(
        eu, 1, H_DIM, I_DIM, (size_t)H_DIM * I_DIM);
    transconv_kernel<<<dim3(H_DIM / 64, I_DIM / 64, E_NUM), 256, 0, stream>>>(
        ed, 2, I_DIM, H_DIM, (size_t)I_DIM * H_DIM);
    transconv_kernel<<<dim3(I_DIM / 64, H_DIM / 64, 1), 256, 0, stream>>>(
        sg, 3, H_DIM, I_DIM, 0);
    transconv_kernel<<<dim3(I_DIM / 64, H_DIM / 64, 1), 256, 0, stream>>>(
        su, 4, H_DIM, I_DIM, 0);
    transconv_kernel<<<dim3(H_DIM / 64, I_DIM / 64, 1), 256, 0, stream>>>(
        sd, 5, I_DIM, H_DIM, 0);

    gemm1_kernel<<<dim3(T_TOK / 128, I_DIM / 64, 9), 256, 0, stream>>>(cnt, offs, tokens);
    gemm2_kernel<<<dim3(T_TOK / 128, H_DIM / 128, 9), 256, 0, stream>>>(cnt, offs, out);
    combine_kernel<<<T_TOK, 256, 0, stream>>>(slotmap, tk_w, out);
}